// Round 1
// baseline (79.484 us; speedup 1.0000x reference)
//
#include <hip/hip_runtime.h>

#define PPB 4  // patches per block (one wave each)

__device__ __forceinline__ float frcp(float x) { return __builtin_amdgcn_rcpf(x); }
__device__ __forceinline__ float fsigmoid(float x) { return frcp(1.0f + __expf(-x)); }
__device__ __forceinline__ float ftanhf(float x) { return 1.0f - 2.0f * frcp(1.0f + __expf(2.0f * x)); }

__global__ __launch_bounds__(256, 4) void rnnpool_kernel(
    const float* __restrict__ inp,
    const float* __restrict__ W1, const float* __restrict__ U1,
    const float* __restrict__ bg1, const float* __restrict__ bu1,
    const float* __restrict__ zeta1, const float* __restrict__ nu1,
    const float* __restrict__ W2, const float* __restrict__ U2,
    const float* __restrict__ bg2, const float* __restrict__ bu2,
    const float* __restrict__ zeta2, const float* __restrict__ nu2,
    float* __restrict__ out)
{
  constexpr int C = 16, U1D = 8, U2D = 16, SH = 4, SW = 4;
  constexpr int OH = 27, OW = 27, HIN = 112, WIN = 112;
  constexpr int XROW = 8 * C + 4;  // padded row stride in floats (132 -> bank-spread)

  __shared__ float xs[PPB][8][XROW];
  __shared__ float hrow[PPB][8][U1D];
  __shared__ float hcol[PPB][8][U1D];

  const int tid = threadIdx.x;
  const int wv = tid >> 6;
  const int lane = tid & 63;
  const int n = blockIdx.x * PPB + wv;
  const int pw = n % OW;
  const int t0 = n / OW;
  const int ph = t0 % OH;
  const int b = t0 / OH;

  // ---- stage 8x8x16 patch into LDS (each lane: one (r,c) pixel, 16 ch) ----
  {
    const int r = lane >> 3, c = lane & 7;
    const float* src = inp + (((size_t)(b * HIN + (ph * SH + r)) * WIN) + (pw * SW + c)) * C;
    const float4* s4 = (const float4*)src;
    float4 v0 = s4[0], v1 = s4[1], v2 = s4[2], v3 = s4[3];
    float* dst = &xs[wv][r][c * C];
    ((float4*)dst)[0] = v0;
    ((float4*)dst)[1] = v1;
    ((float4*)dst)[2] = v2;
    ((float4*)dst)[3] = v3;
  }

  // ---- level-1 per-lane weight columns ----
  const int seq = lane >> 3, hid = lane & 7;
  float w1c[C], u1c[U1D];
#pragma unroll
  for (int ci = 0; ci < C; ++ci) w1c[ci] = W1[ci * U1D + hid];
#pragma unroll
  for (int i = 0; i < U1D; ++i) u1c[i] = U1[i * U1D + hid];
  const float bg1v = bg1[hid], bu1v = bu1[hid];
  const float zg1 = fsigmoid(zeta1[0]), ng1 = fsigmoid(nu1[0]);

  __syncthreads();

  // ---- level-1: row pass (seq = row, t = col) then col pass (seq = col, t = row) ----
#pragma unroll
  for (int pass = 0; pass < 2; ++pass) {
    float h = 0.0f;
#pragma unroll
    for (int t = 0; t < 8; ++t) {
      const float* xv = pass ? &xs[wv][t][seq * C] : &xs[wv][seq][t * C];
      float p0 = 0.f, p1 = 0.f, p2 = 0.f, p3 = 0.f;
#pragma unroll
      for (int ci = 0; ci < C; ci += 4) {
        p0 = fmaf(xv[ci + 0], w1c[ci + 0], p0);
        p1 = fmaf(xv[ci + 1], w1c[ci + 1], p1);
        p2 = fmaf(xv[ci + 2], w1c[ci + 2], p2);
        p3 = fmaf(xv[ci + 3], w1c[ci + 3], p3);
      }
      float q0 = 0.f, q1 = 0.f;
#pragma unroll
      for (int i = 0; i < U1D; i += 2) {
        q0 = fmaf(__shfl(h, i, U1D), u1c[i], q0);
        q1 = fmaf(__shfl(h, i + 1, U1D), u1c[i + 1], q1);
      }
      const float pre = ((p0 + p1) + (p2 + p3)) + (q0 + q1);
      const float z = fsigmoid(pre + bg1v);
      const float cc = ftanhf(pre + bu1v);
      h = z * h + (zg1 * (1.0f - z) + ng1) * cc;
    }
    if (pass)
      hcol[wv][seq][hid] = h;
    else
      hrow[wv][seq][hid] = h;
  }

  // ---- level-2 per-lane weight columns ----
  const int g = lane >> 4, j = lane & 15;
  float w2c[U1D], u2c[U2D];
#pragma unroll
  for (int d = 0; d < U1D; ++d) w2c[d] = W2[d * U2D + j];
#pragma unroll
  for (int i = 0; i < U2D; ++i) u2c[i] = U2[i * U2D + j];
  const float bg2v = bg2[j], bu2v = bu2[j];
  const float zg2 = fsigmoid(zeta2[0]), ng2 = fsigmoid(nu2[0]);

  __syncthreads();

  // ---- level-2: 4 branches x 16 hidden; g0=row fwd, g1=row rev, g2=col fwd, g3=col rev ----
  const float* hbase = (g < 2) ? &hrow[wv][0][0] : &hcol[wv][0][0];
  float h2 = 0.0f;
#pragma unroll
  for (int t = 0; t < 8; ++t) {
    const int tt = (g & 1) ? (7 - t) : t;
    const float* hv = hbase + tt * U1D;
    float p0 = 0.f, p1 = 0.f;
#pragma unroll
    for (int d = 0; d < U1D; d += 2) {
      p0 = fmaf(hv[d + 0], w2c[d + 0], p0);
      p1 = fmaf(hv[d + 1], w2c[d + 1], p1);
    }
    float q0 = 0.f, q1 = 0.f;
#pragma unroll
    for (int i = 0; i < U2D; i += 2) {
      q0 = fmaf(__shfl(h2, i, U2D), u2c[i], q0);
      q1 = fmaf(__shfl(h2, i + 1, U2D), u2c[i + 1], q1);
    }
    const float pre = (p0 + p1) + (q0 + q1);
    const float z = fsigmoid(pre + bg2v);
    const float cc = ftanhf(pre + bu2v);
    h2 = z * h2 + (zg2 * (1.0f - z) + ng2) * cc;
  }

  out[(size_t)n * 64 + lane] = h2;
}

extern "C" void kernel_launch(void* const* d_in, const int* in_sizes, int n_in,
                              void* d_out, int out_size, void* d_ws, size_t ws_size,
                              hipStream_t stream) {
  const float* inp   = (const float*)d_in[0];
  const float* W1    = (const float*)d_in[1];
  const float* U1    = (const float*)d_in[2];
  const float* bg1   = (const float*)d_in[3];
  const float* bu1   = (const float*)d_in[4];
  const float* zeta1 = (const float*)d_in[5];
  const float* nu1   = (const float*)d_in[6];
  const float* W2    = (const float*)d_in[7];
  const float* U2    = (const float*)d_in[8];
  const float* bg2   = (const float*)d_in[9];
  const float* bu2   = (const float*)d_in[10];
  const float* zeta2 = (const float*)d_in[11];
  const float* nu2   = (const float*)d_in[12];
  float* out = (float*)d_out;

  // N = 32 * 27 * 27 = 23328 patches; 4 patches/block
  const int nblocks = 23328 / PPB;  // 5832
  rnnpool_kernel<<<dim3(nblocks), dim3(256), 0, stream>>>(
      inp, W1, U1, bg1, bu1, zeta1, nu1, W2, U2, bg2, bu2, zeta2, nu2, out);
}

// Round 2
// 40.637 us; speedup vs baseline: 1.9559x; 1.9559x over previous
//
#include <hip/hip_runtime.h>

#define PPB 4  // patches per block (one wave each)

__device__ __forceinline__ float frcp(float x) { return __builtin_amdgcn_rcpf(x); }

__global__ __launch_bounds__(256, 4) void rnnpool_kernel(
    const float* __restrict__ inp,
    const float* __restrict__ W1, const float* __restrict__ U1,
    const float* __restrict__ bg1, const float* __restrict__ bu1,
    const float* __restrict__ zeta1, const float* __restrict__ nu1,
    const float* __restrict__ W2, const float* __restrict__ U2,
    const float* __restrict__ bg2, const float* __restrict__ bu2,
    const float* __restrict__ zeta2, const float* __restrict__ nu2,
    float* __restrict__ out)
{
  constexpr int C = 16, SH = 4, SW = 4;
  constexpr int OH = 27, OW = 27, HIN = 112, WIN = 112;
  constexpr int WXROW = 68;  // 8*8 + 4 pad (floats): quad-spread for row reads
  constexpr int HST = 12;    // h row stride: seq*48B -> distinct bank quads
  constexpr int H2ST = 20;   // h2 row stride: g*80B -> distinct bank quads

  __shared__ float w1s[C * 8];              // W1 broadcast copy (128 floats)
  __shared__ float wxs[PPB][8 * WXROW];     // wx[r][c][j], padded rows
  __shared__ float hb[PPB][2][8 * HST];     // [pass][seq*HST+hid]
  __shared__ float h2b[PPB][4 * H2ST];      // [g*H2ST+j]

  const int tid = threadIdx.x, wv = tid >> 6, lane = tid & 63;
  const int n = blockIdx.x * PPB + wv;
  const int pw = n % OW;
  const int q = n / OW;
  const int ph = q % OH, b = q / OH;

  if (tid < 32) ((float4*)w1s)[tid] = ((const float4*)W1)[tid];
  __syncthreads();

  const int r = lane >> 3, cpx = lane & 7;

  // ---- phase 1: wx[j] = x(r,c,:) . W1[:,j] for own pixel, once per patch ----
  {
    const float* src = inp + (((size_t)(b * HIN + (ph * SH + r)) * WIN) + (pw * SW + cpx)) * C;
    float4 x0 = ((const float4*)src)[0], x1 = ((const float4*)src)[1],
           x2 = ((const float4*)src)[2], x3 = ((const float4*)src)[3];
    float xr[16] = {x0.x, x0.y, x0.z, x0.w, x1.x, x1.y, x1.z, x1.w,
                    x2.x, x2.y, x2.z, x2.w, x3.x, x3.y, x3.z, x3.w};
    float a0 = 0.f, a1 = 0.f, a2 = 0.f, a3 = 0.f, a4 = 0.f, a5 = 0.f, a6 = 0.f, a7 = 0.f;
#pragma unroll
    for (int ci = 0; ci < 16; ++ci) {
      float4 wA = *(const float4*)&w1s[ci * 8];      // broadcast (same addr all lanes)
      float4 wB = *(const float4*)&w1s[ci * 8 + 4];
      a0 = fmaf(xr[ci], wA.x, a0);
      a1 = fmaf(xr[ci], wA.y, a1);
      a2 = fmaf(xr[ci], wA.z, a2);
      a3 = fmaf(xr[ci], wA.w, a3);
      a4 = fmaf(xr[ci], wB.x, a4);
      a5 = fmaf(xr[ci], wB.y, a5);
      a6 = fmaf(xr[ci], wB.z, a6);
      a7 = fmaf(xr[ci], wB.w, a7);
    }
    float* wd = &wxs[wv][r * WXROW + cpx * 8];
    *(float4*)wd = float4{a0, a1, a2, a3};
    *(float4*)(wd + 4) = float4{a4, a5, a6, a7};
  }
  __builtin_amdgcn_wave_barrier();

  // ---- phase 2: level-1 recurrences (row pass p=0, col pass p=1) ----
  const int seq = r, hid = cpx;
  float u1c[8];
#pragma unroll
  for (int i = 0; i < 8; ++i) u1c[i] = U1[i * 8 + hid];
  const float bg1v = bg1[hid], bu1v = bu1[hid];
  const float zg1 = frcp(1.f + __expf(-zeta1[0]));
  const float ng1 = frcp(1.f + __expf(-nu1[0]));
  const float A1 = zg1 + ng1;
  const float K1 = __expf(2.f * (bg1v - bu1v));

#pragma unroll
  for (int p = 0; p < 2; ++p) {
    float* hp = &hb[wv][p][0];
    float h;
    {  // t = 0, h == 0
      float pre = (p == 0) ? wxs[wv][seq * WXROW + hid] : wxs[wv][seq * 8 + hid];
      float s = __expf(-(pre + bg1v));
      float z = frcp(1.f + s);
      float u = s * s * K1;
      float cc = fmaf(2.f, frcp(1.f + u), -1.f);
      float m = fmaf(-zg1, z, A1);
      h = m * cc;
      hp[seq * HST + hid] = h;
    }
    __builtin_amdgcn_wave_barrier();
#pragma unroll
    for (int t = 1; t < 8; ++t) {
      float4 h0 = *(const float4*)&hp[seq * HST];
      float4 h1 = *(const float4*)&hp[seq * HST + 4];
      float qa = h0.x * u1c[0], qb = h0.y * u1c[1];
      qa = fmaf(h0.z, u1c[2], qa);
      qb = fmaf(h0.w, u1c[3], qb);
      qa = fmaf(h1.x, u1c[4], qa);
      qb = fmaf(h1.y, u1c[5], qb);
      qa = fmaf(h1.z, u1c[6], qa);
      qb = fmaf(h1.w, u1c[7], qb);
      float wxv = (p == 0) ? wxs[wv][seq * WXROW + t * 8 + hid]
                           : wxs[wv][t * WXROW + seq * 8 + hid];
      float pre = wxv + qa + qb;
      float s = __expf(-(pre + bg1v));
      float z = frcp(1.f + s);
      float u = s * s * K1;
      float cc = fmaf(2.f, frcp(1.f + u), -1.f);
      float m = fmaf(-zg1, z, A1);
      h = fmaf(z, h, m * cc);
      hp[seq * HST + hid] = h;
      __builtin_amdgcn_wave_barrier();
    }
  }

  // ---- phase 3: level-2, 4 branches x 16 hidden ----
  const int g = lane >> 4, j = lane & 15;
  float w2c[8], u2c[16];
#pragma unroll
  for (int d = 0; d < 8; ++d) w2c[d] = W2[d * 16 + j];
#pragma unroll
  for (int i = 0; i < 16; ++i) u2c[i] = U2[i * 16 + j];
  const float bg2v = bg2[j], bu2v = bu2[j];
  const float zg2 = frcp(1.f + __expf(-zeta2[0]));
  const float ng2 = frcp(1.f + __expf(-nu2[0]));
  const float A2 = zg2 + ng2;
  const float K2 = __expf(2.f * (bg2v - bu2v));
  const float* hsrc = &hb[wv][g >> 1][0];

  float h2;
  {  // t = 0, h2 == 0
    const int tt = (g & 1) ? 7 : 0;
    const float4 a = *(const float4*)&hsrc[tt * HST];
    const float4 bq = *(const float4*)&hsrc[tt * HST + 4];
    float pa = a.x * w2c[0], pb = a.y * w2c[1];
    pa = fmaf(a.z, w2c[2], pa);
    pb = fmaf(a.w, w2c[3], pb);
    pa = fmaf(bq.x, w2c[4], pa);
    pb = fmaf(bq.y, w2c[5], pb);
    pa = fmaf(bq.z, w2c[6], pa);
    pb = fmaf(bq.w, w2c[7], pb);
    float pre = pa + pb;
    float s = __expf(-(pre + bg2v));
    float z = frcp(1.f + s);
    float u = s * s * K2;
    float cc = fmaf(2.f, frcp(1.f + u), -1.f);
    float m = fmaf(-zg2, z, A2);
    h2 = m * cc;
    h2b[wv][g * H2ST + j] = h2;
  }
  __builtin_amdgcn_wave_barrier();
#pragma unroll
  for (int t = 1; t < 8; ++t) {
    const int tt = (g & 1) ? (7 - t) : t;
    const float4 a = *(const float4*)&hsrc[tt * HST];
    const float4 bq = *(const float4*)&hsrc[tt * HST + 4];
    float pa = a.x * w2c[0], pb = a.y * w2c[1];
    pa = fmaf(a.z, w2c[2], pa);
    pb = fmaf(a.w, w2c[3], pb);
    pa = fmaf(bq.x, w2c[4], pa);
    pb = fmaf(bq.y, w2c[5], pb);
    pa = fmaf(bq.z, w2c[6], pa);
    pb = fmaf(bq.w, w2c[7], pb);

    const float* h2v = &h2b[wv][g * H2ST];
    const float4 v0 = *(const float4*)h2v;
    const float4 v1 = *(const float4*)(h2v + 4);
    const float4 v2 = *(const float4*)(h2v + 8);
    const float4 v3 = *(const float4*)(h2v + 12);
    float qa = v0.x * u2c[0], qb = v0.y * u2c[1];
    qa = fmaf(v0.z, u2c[2], qa);
    qb = fmaf(v0.w, u2c[3], qb);
    qa = fmaf(v1.x, u2c[4], qa);
    qb = fmaf(v1.y, u2c[5], qb);
    qa = fmaf(v1.z, u2c[6], qa);
    qb = fmaf(v1.w, u2c[7], qb);
    qa = fmaf(v2.x, u2c[8], qa);
    qb = fmaf(v2.y, u2c[9], qb);
    qa = fmaf(v2.z, u2c[10], qa);
    qb = fmaf(v2.w, u2c[11], qb);
    qa = fmaf(v3.x, u2c[12], qa);
    qb = fmaf(v3.y, u2c[13], qb);
    qa = fmaf(v3.z, u2c[14], qa);
    qb = fmaf(v3.w, u2c[15], qb);

    float pre = (pa + pb) + (qa + qb);
    float s = __expf(-(pre + bg2v));
    float z = frcp(1.f + s);
    float u = s * s * K2;
    float cc = fmaf(2.f, frcp(1.f + u), -1.f);
    float m = fmaf(-zg2, z, A2);
    h2 = fmaf(z, h2, m * cc);
    if (t < 7) {
      h2b[wv][g * H2ST + j] = h2;
      __builtin_amdgcn_wave_barrier();
    }
  }

  out[(size_t)n * 64 + lane] = h2;
}

extern "C" void kernel_launch(void* const* d_in, const int* in_sizes, int n_in,
                              void* d_out, int out_size, void* d_ws, size_t ws_size,
                              hipStream_t stream) {
  const float* inp   = (const float*)d_in[0];
  const float* W1    = (const float*)d_in[1];
  const float* U1    = (const float*)d_in[2];
  const float* bg1   = (const float*)d_in[3];
  const float* bu1   = (const float*)d_in[4];
  const float* zeta1 = (const float*)d_in[5];
  const float* nu1   = (const float*)d_in[6];
  const float* W2    = (const float*)d_in[7];
  const float* U2    = (const float*)d_in[8];
  const float* bg2   = (const float*)d_in[9];
  const float* bu2   = (const float*)d_in[10];
  const float* zeta2 = (const float*)d_in[11];
  const float* nu2   = (const float*)d_in[12];
  float* out = (float*)d_out;

  const int nblocks = 23328 / PPB;  // 32*27*27 patches, 4 per block
  rnnpool_kernel<<<dim3(nblocks), dim3(256), 0, stream>>>(
      inp, W1, U1, bg1, bu1, zeta1, nu1, W2, U2, bg2, bu2, zeta2, nu2, out);
}

// Round 3
// 40.157 us; speedup vs baseline: 1.9793x; 1.0120x over previous
//
#include <hip/hip_runtime.h>

#define PPB 4  // waves (work items) per 256-thread block

__device__ __forceinline__ float frcp(float x) { return __builtin_amdgcn_rcpf(x); }

// ---------------- Kernel A: deduplicated level-1 recurrences ----------------
// Row recs (b, y, pw): seq over 8 cols of window pw. Col recs (b, x, ph): seq
// over 8 rows of window ph. One wave = 8 recurrences sharing an 8x8 pixel tile.
__global__ __launch_bounds__(256, 4) void l1_kernel(
    const float* __restrict__ inp,
    const float* __restrict__ W1, const float* __restrict__ U1,
    const float* __restrict__ bg1, const float* __restrict__ bu1,
    const float* __restrict__ zeta1, const float* __restrict__ nu1,
    float* __restrict__ hrowg, float* __restrict__ hcolg)
{
  constexpr int C = 16, HIN = 112, WIN = 112;
  constexpr int NROW = 32 * 14 * 27;  // 12096 row-mode waves
  constexpr int WXROW = 68;           // 8*8 + 4 pad floats
  constexpr int HST = 12;

  __shared__ float w1s[C * 8];
  __shared__ float wxs[PPB][8 * WXROW];
  __shared__ float hbuf[PPB][8 * HST];

  const int tid = threadIdx.x, wv = tid >> 6, lane = tid & 63;
  const int widx = blockIdx.x * PPB + wv;

  if (tid < 32) ((float4*)w1s)[tid] = ((const float4*)W1)[tid];
  __syncthreads();

  const bool isrow = widx < NROW;
  const int v = isrow ? widx : widx - NROW;
  const int b = v / 378;        // 378 = 14*27
  const int rem = v % 378;
  const int t14 = rem / 27;     // 8-wide tile index (y-tile for row, x-tile for col)
  const int t27 = rem % 27;     // window index (pw for row, ph for col)
  const int ybase = isrow ? t14 * 8 : t27 * 4;
  const int xbase = isrow ? t27 * 4 : t14 * 8;

  const int r = lane >> 3, cpx = lane & 7;

  // ---- wx[j] = x(pixel) . W1[:,j], pixel = (ybase+r, xbase+cpx) ----
  {
    const float* src = inp + (((size_t)(b * HIN + ybase + r) * WIN) + xbase + cpx) * C;
    float4 x0 = ((const float4*)src)[0], x1 = ((const float4*)src)[1],
           x2 = ((const float4*)src)[2], x3 = ((const float4*)src)[3];
    float xr[16] = {x0.x, x0.y, x0.z, x0.w, x1.x, x1.y, x1.z, x1.w,
                    x2.x, x2.y, x2.z, x2.w, x3.x, x3.y, x3.z, x3.w};
    float a0 = 0.f, a1 = 0.f, a2 = 0.f, a3 = 0.f, a4 = 0.f, a5 = 0.f, a6 = 0.f, a7 = 0.f;
#pragma unroll
    for (int ci = 0; ci < 16; ++ci) {
      float4 wA = *(const float4*)&w1s[ci * 8];
      float4 wB = *(const float4*)&w1s[ci * 8 + 4];
      a0 = fmaf(xr[ci], wA.x, a0);
      a1 = fmaf(xr[ci], wA.y, a1);
      a2 = fmaf(xr[ci], wA.z, a2);
      a3 = fmaf(xr[ci], wA.w, a3);
      a4 = fmaf(xr[ci], wB.x, a4);
      a5 = fmaf(xr[ci], wB.y, a5);
      a6 = fmaf(xr[ci], wB.z, a6);
      a7 = fmaf(xr[ci], wB.w, a7);
    }
    float* wd = &wxs[wv][r * WXROW + cpx * 8];
    *(float4*)wd = float4{a0, a1, a2, a3};
    *(float4*)(wd + 4) = float4{a4, a5, a6, a7};
  }
  __builtin_amdgcn_wave_barrier();

  // ---- 8-step recurrence: seq = lane>>3 selects the recurrence, hid = lane&7 ----
  const int seq = r, hid = cpx;
  float u1c[8];
#pragma unroll
  for (int i = 0; i < 8; ++i) u1c[i] = U1[i * 8 + hid];
  const float bg1v = bg1[hid], bu1v = bu1[hid];
  const float zg1 = frcp(1.f + __expf(-zeta1[0]));
  const float ng1 = frcp(1.f + __expf(-nu1[0]));
  const float A1 = zg1 + ng1;
  const float K1 = __expf(2.f * (bg1v - bu1v));

  float* hp = &hbuf[wv][0];
  float h;
  auto run = [&](int off0, int step) {
    {  // t = 0 (h == 0)
      float pre = wxs[wv][off0];
      float s = __expf(-(pre + bg1v));
      float z = frcp(1.f + s);
      float u = s * s * K1;
      float cc = fmaf(2.f, frcp(1.f + u), -1.f);
      float m = fmaf(-zg1, z, A1);
      h = m * cc;
      hp[seq * HST + hid] = h;
    }
    __builtin_amdgcn_wave_barrier();
#pragma unroll
    for (int t = 1; t < 8; ++t) {
      float4 h0 = *(const float4*)&hp[seq * HST];
      float4 h1 = *(const float4*)&hp[seq * HST + 4];
      float qa = h0.x * u1c[0], qb = h0.y * u1c[1];
      qa = fmaf(h0.z, u1c[2], qa);
      qb = fmaf(h0.w, u1c[3], qb);
      qa = fmaf(h1.x, u1c[4], qa);
      qb = fmaf(h1.y, u1c[5], qb);
      qa = fmaf(h1.z, u1c[6], qa);
      qb = fmaf(h1.w, u1c[7], qb);
      float pre = wxs[wv][off0 + t * step] + qa + qb;
      float s = __expf(-(pre + bg1v));
      float z = frcp(1.f + s);
      float u = s * s * K1;
      float cc = fmaf(2.f, frcp(1.f + u), -1.f);
      float m = fmaf(-zg1, z, A1);
      h = fmaf(z, h, m * cc);
      hp[seq * HST + hid] = h;
      __builtin_amdgcn_wave_barrier();
    }
  };
  if (isrow)
    run(seq * WXROW + hid, 8);    // along columns of row seq
  else
    run(seq * 8 + hid, WXROW);    // along rows of column seq

  // out: hrowg[b][pw][y][hid] / hcolg[b][ph][x][hid]; y|x = t14*8+seq
  const size_t oidx = (((size_t)(b * 27 + t27) * 112) + t14 * 8 + seq) * 8 + hid;
  (isrow ? hrowg : hcolg)[oidx] = h;
}

// ---------------- Kernel B: level-2, one wave per patch ----------------
__global__ __launch_bounds__(256, 4) void l2_kernel(
    const float* __restrict__ hrowg, const float* __restrict__ hcolg,
    const float* __restrict__ W2, const float* __restrict__ U2,
    const float* __restrict__ bg2, const float* __restrict__ bu2,
    const float* __restrict__ zeta2, const float* __restrict__ nu2,
    float* __restrict__ out)
{
  constexpr int H2ST = 20;
  __shared__ float hb[PPB][2][64];
  __shared__ float h2b[PPB][4 * H2ST];

  const int tid = threadIdx.x, wv = tid >> 6, lane = tid & 63;
  const int n = blockIdx.x * PPB + wv;
  const int pw = n % 27;
  const int q = n / 27;
  const int ph = q % 27, b = q / 27;

  // stage this patch's hrow (8x8) and hcol (8x8), each 256B contiguous
  if (lane < 32) {
    const int half = lane >> 4, idx = lane & 15;
    const float* src = half ? &hcolg[(((size_t)(b * 27 + ph) * 112) + pw * 4) * 8]
                            : &hrowg[(((size_t)(b * 27 + pw) * 112) + ph * 4) * 8];
    ((float4*)&hb[wv][half][0])[idx] = ((const float4*)src)[idx];
  }
  __builtin_amdgcn_wave_barrier();

  const int g = lane >> 4, j = lane & 15;
  float w2c[8], u2c[16];
#pragma unroll
  for (int d = 0; d < 8; ++d) w2c[d] = W2[d * 16 + j];
#pragma unroll
  for (int i = 0; i < 16; ++i) u2c[i] = U2[i * 16 + j];
  const float bg2v = bg2[j], bu2v = bu2[j];
  const float zg2 = frcp(1.f + __expf(-zeta2[0]));
  const float ng2 = frcp(1.f + __expf(-nu2[0]));
  const float A2 = zg2 + ng2;
  const float K2 = __expf(2.f * (bg2v - bu2v));
  const float* hsrc = &hb[wv][g >> 1][0];

  float h2;
  {  // t = 0 (h2 == 0)
    const int tt = (g & 1) ? 7 : 0;
    const float4 a = *(const float4*)&hsrc[tt * 8];
    const float4 bq = *(const float4*)&hsrc[tt * 8 + 4];
    float pa = a.x * w2c[0], pb = a.y * w2c[1];
    pa = fmaf(a.z, w2c[2], pa);
    pb = fmaf(a.w, w2c[3], pb);
    pa = fmaf(bq.x, w2c[4], pa);
    pb = fmaf(bq.y, w2c[5], pb);
    pa = fmaf(bq.z, w2c[6], pa);
    pb = fmaf(bq.w, w2c[7], pb);
    float pre = pa + pb;
    float s = __expf(-(pre + bg2v));
    float z = frcp(1.f + s);
    float u = s * s * K2;
    float cc = fmaf(2.f, frcp(1.f + u), -1.f);
    float m = fmaf(-zg2, z, A2);
    h2 = m * cc;
    h2b[wv][g * H2ST + j] = h2;
  }
  __builtin_amdgcn_wave_barrier();
#pragma unroll
  for (int t = 1; t < 8; ++t) {
    const int tt = (g & 1) ? (7 - t) : t;
    const float4 a = *(const float4*)&hsrc[tt * 8];
    const float4 bq = *(const float4*)&hsrc[tt * 8 + 4];
    float pa = a.x * w2c[0], pb = a.y * w2c[1];
    pa = fmaf(a.z, w2c[2], pa);
    pb = fmaf(a.w, w2c[3], pb);
    pa = fmaf(bq.x, w2c[4], pa);
    pb = fmaf(bq.y, w2c[5], pb);
    pa = fmaf(bq.z, w2c[6], pa);
    pb = fmaf(bq.w, w2c[7], pb);

    const float* h2v = &h2b[wv][g * H2ST];
    const float4 v0 = *(const float4*)h2v;
    const float4 v1 = *(const float4*)(h2v + 4);
    const float4 v2 = *(const float4*)(h2v + 8);
    const float4 v3 = *(const float4*)(h2v + 12);
    float qa = v0.x * u2c[0], qb = v0.y * u2c[1];
    qa = fmaf(v0.z, u2c[2], qa);
    qb = fmaf(v0.w, u2c[3], qb);
    qa = fmaf(v1.x, u2c[4], qa);
    qb = fmaf(v1.y, u2c[5], qb);
    qa = fmaf(v1.z, u2c[6], qa);
    qb = fmaf(v1.w, u2c[7], qb);
    qa = fmaf(v2.x, u2c[8], qa);
    qb = fmaf(v2.y, u2c[9], qb);
    qa = fmaf(v2.z, u2c[10], qa);
    qb = fmaf(v2.w, u2c[11], qb);
    qa = fmaf(v3.x, u2c[12], qa);
    qb = fmaf(v3.y, u2c[13], qb);
    qa = fmaf(v3.z, u2c[14], qa);
    qb = fmaf(v3.w, u2c[15], qb);

    float pre = (pa + pb) + (qa + qb);
    float s = __expf(-(pre + bg2v));
    float z = frcp(1.f + s);
    float u = s * s * K2;
    float cc = fmaf(2.f, frcp(1.f + u), -1.f);
    float m = fmaf(-zg2, z, A2);
    h2 = fmaf(z, h2, m * cc);
    if (t < 7) {
      h2b[wv][g * H2ST + j] = h2;
      __builtin_amdgcn_wave_barrier();
    }
  }

  out[(size_t)n * 64 + lane] = h2;
}

// ---------------- Fallback: round-2 monolithic kernel (if ws too small) ----------------
__global__ __launch_bounds__(256, 4) void rnnpool_mono(
    const float* __restrict__ inp,
    const float* __restrict__ W1, const float* __restrict__ U1,
    const float* __restrict__ bg1, const float* __restrict__ bu1,
    const float* __restrict__ zeta1, const float* __restrict__ nu1,
    const float* __restrict__ W2, const float* __restrict__ U2,
    const float* __restrict__ bg2, const float* __restrict__ bu2,
    const float* __restrict__ zeta2, const float* __restrict__ nu2,
    float* __restrict__ out)
{
  constexpr int C = 16, SH = 4, SW = 4;
  constexpr int OH = 27, OW = 27, HIN = 112, WIN = 112;
  constexpr int WXROW = 68;
  constexpr int HST = 12;
  constexpr int H2ST = 20;

  __shared__ float w1s[C * 8];
  __shared__ float wxs[PPB][8 * WXROW];
  __shared__ float hb[PPB][2][8 * HST];
  __shared__ float h2b[PPB][4 * H2ST];

  const int tid = threadIdx.x, wv = tid >> 6, lane = tid & 63;
  const int n = blockIdx.x * PPB + wv;
  const int pw = n % OW;
  const int q = n / OW;
  const int ph = q % OH, b = q / OH;

  if (tid < 32) ((float4*)w1s)[tid] = ((const float4*)W1)[tid];
  __syncthreads();

  const int r = lane >> 3, cpx = lane & 7;
  {
    const float* src = inp + (((size_t)(b * HIN + (ph * SH + r)) * WIN) + (pw * SW + cpx)) * C;
    float4 x0 = ((const float4*)src)[0], x1 = ((const float4*)src)[1],
           x2 = ((const float4*)src)[2], x3 = ((const float4*)src)[3];
    float xr[16] = {x0.x, x0.y, x0.z, x0.w, x1.x, x1.y, x1.z, x1.w,
                    x2.x, x2.y, x2.z, x2.w, x3.x, x3.y, x3.z, x3.w};
    float a0 = 0.f, a1 = 0.f, a2 = 0.f, a3 = 0.f, a4 = 0.f, a5 = 0.f, a6 = 0.f, a7 = 0.f;
#pragma unroll
    for (int ci = 0; ci < 16; ++ci) {
      float4 wA = *(const float4*)&w1s[ci * 8];
      float4 wB = *(const float4*)&w1s[ci * 8 + 4];
      a0 = fmaf(xr[ci], wA.x, a0);
      a1 = fmaf(xr[ci], wA.y, a1);
      a2 = fmaf(xr[ci], wA.z, a2);
      a3 = fmaf(xr[ci], wA.w, a3);
      a4 = fmaf(xr[ci], wB.x, a4);
      a5 = fmaf(xr[ci], wB.y, a5);
      a6 = fmaf(xr[ci], wB.z, a6);
      a7 = fmaf(xr[ci], wB.w, a7);
    }
    float* wd = &wxs[wv][r * WXROW + cpx * 8];
    *(float4*)wd = float4{a0, a1, a2, a3};
    *(float4*)(wd + 4) = float4{a4, a5, a6, a7};
  }
  __builtin_amdgcn_wave_barrier();

  const int seq = r, hid = cpx;
  float u1c[8];
#pragma unroll
  for (int i = 0; i < 8; ++i) u1c[i] = U1[i * 8 + hid];
  const float bg1v = bg1[hid], bu1v = bu1[hid];
  const float zg1 = frcp(1.f + __expf(-zeta1[0]));
  const float ng1 = frcp(1.f + __expf(-nu1[0]));
  const float A1 = zg1 + ng1;
  const float K1 = __expf(2.f * (bg1v - bu1v));

#pragma unroll
  for (int p = 0; p < 2; ++p) {
    float* hp = &hb[wv][p][0];
    float h;
    {
      float pre = (p == 0) ? wxs[wv][seq * WXROW + hid] : wxs[wv][seq * 8 + hid];
      float s = __expf(-(pre + bg1v));
      float z = frcp(1.f + s);
      float u = s * s * K1;
      float cc = fmaf(2.f, frcp(1.f + u), -1.f);
      float m = fmaf(-zg1, z, A1);
      h = m * cc;
      hp[seq * HST + hid] = h;
    }
    __builtin_amdgcn_wave_barrier();
#pragma unroll
    for (int t = 1; t < 8; ++t) {
      float4 h0 = *(const float4*)&hp[seq * HST];
      float4 h1 = *(const float4*)&hp[seq * HST + 4];
      float qa = h0.x * u1c[0], qb = h0.y * u1c[1];
      qa = fmaf(h0.z, u1c[2], qa);
      qb = fmaf(h0.w, u1c[3], qb);
      qa = fmaf(h1.x, u1c[4], qa);
      qb = fmaf(h1.y, u1c[5], qb);
      qa = fmaf(h1.z, u1c[6], qa);
      qb = fmaf(h1.w, u1c[7], qb);
      float wxv = (p == 0) ? wxs[wv][seq * WXROW + t * 8 + hid]
                           : wxs[wv][t * WXROW + seq * 8 + hid];
      float pre = wxv + qa + qb;
      float s = __expf(-(pre + bg1v));
      float z = frcp(1.f + s);
      float u = s * s * K1;
      float cc = fmaf(2.f, frcp(1.f + u), -1.f);
      float m = fmaf(-zg1, z, A1);
      h = fmaf(z, h, m * cc);
      hp[seq * HST + hid] = h;
      __builtin_amdgcn_wave_barrier();
    }
  }

  const int g = lane >> 4, j = lane & 15;
  float w2c[8], u2c[16];
#pragma unroll
  for (int d = 0; d < 8; ++d) w2c[d] = W2[d * 16 + j];
#pragma unroll
  for (int i = 0; i < 16; ++i) u2c[i] = U2[i * 16 + j];
  const float bg2v = bg2[j], bu2v = bu2[j];
  const float zg2 = frcp(1.f + __expf(-zeta2[0]));
  const float ng2 = frcp(1.f + __expf(-nu2[0]));
  const float A2 = zg2 + ng2;
  const float K2 = __expf(2.f * (bg2v - bu2v));
  const float* hsrc = &hb[wv][g >> 1][0];

  float h2;
  {
    const int tt = (g & 1) ? 7 : 0;
    const float4 a = *(const float4*)&hsrc[tt * HST];
    const float4 bq = *(const float4*)&hsrc[tt * HST + 4];
    float pa = a.x * w2c[0], pb = a.y * w2c[1];
    pa = fmaf(a.z, w2c[2], pa);
    pb = fmaf(a.w, w2c[3], pb);
    pa = fmaf(bq.x, w2c[4], pa);
    pb = fmaf(bq.y, w2c[5], pb);
    pa = fmaf(bq.z, w2c[6], pa);
    pb = fmaf(bq.w, w2c[7], pb);
    float pre = pa + pb;
    float s = __expf(-(pre + bg2v));
    float z = frcp(1.f + s);
    float u = s * s * K2;
    float cc = fmaf(2.f, frcp(1.f + u), -1.f);
    float m = fmaf(-zg2, z, A2);
    h2 = m * cc;
    h2b[wv][g * H2ST + j] = h2;
  }
  __builtin_amdgcn_wave_barrier();
#pragma unroll
  for (int t = 1; t < 8; ++t) {
    const int tt = (g & 1) ? (7 - t) : t;
    const float4 a = *(const float4*)&hsrc[tt * HST];
    const float4 bq = *(const float4*)&hsrc[tt * HST + 4];
    float pa = a.x * w2c[0], pb = a.y * w2c[1];
    pa = fmaf(a.z, w2c[2], pa);
    pb = fmaf(a.w, w2c[3], pb);
    pa = fmaf(bq.x, w2c[4], pa);
    pb = fmaf(bq.y, w2c[5], pb);
    pa = fmaf(bq.z, w2c[6], pa);
    pb = fmaf(bq.w, w2c[7], pb);
    const float* h2v = &h2b[wv][g * H2ST];
    const float4 v0 = *(const float4*)h2v;
    const float4 v1 = *(const float4*)(h2v + 4);
    const float4 v2 = *(const float4*)(h2v + 8);
    const float4 v3 = *(const float4*)(h2v + 12);
    float qa = v0.x * u2c[0], qb = v0.y * u2c[1];
    qa = fmaf(v0.z, u2c[2], qa);
    qb = fmaf(v0.w, u2c[3], qb);
    qa = fmaf(v1.x, u2c[4], qa);
    qb = fmaf(v1.y, u2c[5], qb);
    qa = fmaf(v1.z, u2c[6], qa);
    qb = fmaf(v1.w, u2c[7], qb);
    qa = fmaf(v2.x, u2c[8], qa);
    qb = fmaf(v2.y, u2c[9], qb);
    qa = fmaf(v2.z, u2c[10], qa);
    qb = fmaf(v2.w, u2c[11], qb);
    qa = fmaf(v3.x, u2c[12], qa);
    qb = fmaf(v3.y, u2c[13], qb);
    qa = fmaf(v3.z, u2c[14], qa);
    qb = fmaf(v3.w, u2c[15], qb);
    float pre = (pa + pb) + (qa + qb);
    float s = __expf(-(pre + bg2v));
    float z = frcp(1.f + s);
    float u = s * s * K2;
    float cc = fmaf(2.f, frcp(1.f + u), -1.f);
    float m = fmaf(-zg2, z, A2);
    h2 = fmaf(z, h2, m * cc);
    if (t < 7) {
      h2b[wv][g * H2ST + j] = h2;
      __builtin_amdgcn_wave_barrier();
    }
  }
  out[(size_t)n * 64 + lane] = h2;
}

extern "C" void kernel_launch(void* const* d_in, const int* in_sizes, int n_in,
                              void* d_out, int out_size, void* d_ws, size_t ws_size,
                              hipStream_t stream) {
  const float* inp   = (const float*)d_in[0];
  const float* W1    = (const float*)d_in[1];
  const float* U1    = (const float*)d_in[2];
  const float* bg1   = (const float*)d_in[3];
  const float* bu1   = (const float*)d_in[4];
  const float* zeta1 = (const float*)d_in[5];
  const float* nu1   = (const float*)d_in[6];
  const float* W2    = (const float*)d_in[7];
  const float* U2    = (const float*)d_in[8];
  const float* bg2   = (const float*)d_in[9];
  const float* bu2   = (const float*)d_in[10];
  const float* zeta2 = (const float*)d_in[11];
  const float* nu2   = (const float*)d_in[12];
  float* out = (float*)d_out;

  const size_t HSZ = (size_t)32 * 27 * 112 * 8;  // floats per h buffer (3.1 MB)
  if (ws_size >= 2 * HSZ * sizeof(float)) {
    float* hrowg = (float*)d_ws;
    float* hcolg = hrowg + HSZ;
    // Kernel A: 2*12096 waves, 4/block -> 6048 blocks
    l1_kernel<<<dim3(6048), dim3(256), 0, stream>>>(
        inp, W1, U1, bg1, bu1, zeta1, nu1, hrowg, hcolg);
    // Kernel B: 23328 patches, 4/block -> 5832 blocks
    l2_kernel<<<dim3(5832), dim3(256), 0, stream>>>(
        hrowg, hcolg, W2, U2, bg2, bu2, zeta2, nu2, out);
  } else {
    rnnpool_mono<<<dim3(23328 / PPB), dim3(256), 0, stream>>>(
        inp, W1, U1, bg1, bu1, zeta1, nu1, W2, U2, bg2, bu2, zeta2, nu2, out);
  }
}

// Round 5
// 37.657 us; speedup vs baseline: 2.1107x; 1.0664x over previous
//
#include <hip/hip_runtime.h>

#define PPB 4  // waves per 256-thread block

typedef float v2f __attribute__((ext_vector_type(2)));

__device__ __forceinline__ float frcp(float x) { return __builtin_amdgcn_rcpf(x); }

__device__ __forceinline__ v2f vfma2(v2f a, v2f b, v2f c) {
#if __has_builtin(__builtin_elementwise_fma)
  return __builtin_elementwise_fma(a, b, c);
#else
  v2f d; d.x = fmaf(a.x, b.x, c.x); d.y = fmaf(a.y, b.y, c.y); return d;
#endif
}
__device__ __forceinline__ v2f bc(float x) { v2f p; p.x = x; p.y = x; return p; }

// packed FastGRNN gate update (2 independent recurrences per lane)
__device__ __forceinline__ v2f gate2(v2f pre, v2f h, v2f bgB, v2f KB, v2f nzgB,
                                     v2f AB, bool first) {
  v2f a = pre + bgB;
  v2f s; s.x = __expf(-a.x); s.y = __expf(-a.y);
  v2f one = bc(1.f);
  v2f zd = s + one;
  v2f z; z.x = frcp(zd.x); z.y = frcp(zd.y);
  v2f u = (s * s) * KB;
  v2f cd = u + one;
  v2f cr; cr.x = frcp(cd.x); cr.y = frcp(cd.y);
  v2f cc = vfma2(cr, bc(2.f), bc(-1.f));
  v2f m = vfma2(z, nzgB, AB);
  v2f mc = m * cc;
  return first ? mc : vfma2(z, h, mc);
}

// ---------------- Kernel A: dedup'd level-1, 2 tiles (packed) per wave ----------------
__global__ __launch_bounds__(256) void l1_kernel(
    const float* __restrict__ inp, const float* __restrict__ W1,
    const float* __restrict__ U1, const float* __restrict__ bg1,
    const float* __restrict__ bu1, const float* __restrict__ zeta1,
    const float* __restrict__ nu1, float* __restrict__ hrowg,
    float* __restrict__ hcolg) {
  constexpr int NP = 6048;   // 32 * 7 * 27 pair-waves per mode
  constexpr int SAs = 68;    // wx scalar a-row stride (floats)
  constexpr int SH = 18;     // hp seq stride (v2 units)

  __shared__ float w1s[128];
  __shared__ float wxs[PPB][16 * SAs];
  __shared__ v2f hp[PPB][7 * SH + 8];

  const int tid = threadIdx.x, wv = tid >> 6, lane = tid & 63;
  const int widx = blockIdx.x * PPB + wv;

  if (tid < 32) ((float4*)w1s)[tid] = ((const float4*)W1)[tid];
  __syncthreads();

  const bool isrow = widx < NP;
  const int v = isrow ? widx : widx - NP;
  const int b = v / 189;        // 7*27
  const int rem = v % 189;
  const int k = rem / 27;       // tile-pair index (0..6)
  const int t27 = rem % 27;     // window index

  const int rr = lane >> 3, cc = lane & 7;
  // pixel A (tile0) and B (tile1)
  const int ay = isrow ? (k * 16 + rr) : (t27 * 4 + rr);
  const int ax = isrow ? (t27 * 4 + cc) : (k * 16 + cc);
  const int by = isrow ? (ay + 8) : ay;
  const int bx = isrow ? ax : (ax + 8);

  // ---- wx for both pixels (scalar, weights shared) ----
  {
    const float* pA = inp + ((size_t)(b * 112 + ay) * 112 + ax) * 16;
    const float* pB = inp + ((size_t)(b * 112 + by) * 112 + bx) * 16;
    float4 A0 = ((const float4*)pA)[0], A1 = ((const float4*)pA)[1],
           A2 = ((const float4*)pA)[2], A3 = ((const float4*)pA)[3];
    float4 B0 = ((const float4*)pB)[0], B1 = ((const float4*)pB)[1],
           B2 = ((const float4*)pB)[2], B3 = ((const float4*)pB)[3];
    float xA[16] = {A0.x, A0.y, A0.z, A0.w, A1.x, A1.y, A1.z, A1.w,
                    A2.x, A2.y, A2.z, A2.w, A3.x, A3.y, A3.z, A3.w};
    float xB[16] = {B0.x, B0.y, B0.z, B0.w, B1.x, B1.y, B1.z, B1.w,
                    B2.x, B2.y, B2.z, B2.w, B3.x, B3.y, B3.z, B3.w};
    float aA[8] = {0, 0, 0, 0, 0, 0, 0, 0};
    float aB[8] = {0, 0, 0, 0, 0, 0, 0, 0};
#pragma unroll
    for (int ci = 0; ci < 16; ++ci) {
      float4 wL = *(const float4*)&w1s[ci * 8];
      float4 wH = *(const float4*)&w1s[ci * 8 + 4];
      aA[0] = fmaf(xA[ci], wL.x, aA[0]); aA[1] = fmaf(xA[ci], wL.y, aA[1]);
      aA[2] = fmaf(xA[ci], wL.z, aA[2]); aA[3] = fmaf(xA[ci], wL.w, aA[3]);
      aA[4] = fmaf(xA[ci], wH.x, aA[4]); aA[5] = fmaf(xA[ci], wH.y, aA[5]);
      aA[6] = fmaf(xA[ci], wH.z, aA[6]); aA[7] = fmaf(xA[ci], wH.w, aA[7]);
      aB[0] = fmaf(xB[ci], wL.x, aB[0]); aB[1] = fmaf(xB[ci], wL.y, aB[1]);
      aB[2] = fmaf(xB[ci], wL.z, aB[2]); aB[3] = fmaf(xB[ci], wL.w, aB[3]);
      aB[4] = fmaf(xB[ci], wH.x, aB[4]); aB[5] = fmaf(xB[ci], wH.y, aB[5]);
      aB[6] = fmaf(xB[ci], wH.z, aB[6]); aB[7] = fmaf(xB[ci], wH.w, aB[7]);
    }
    // store: row-mode (a,b) = (rr,cc); col-mode (a,b) = (cc,rr); tile1 at a+8
    const int a0 = isrow ? rr : cc;
    const int b0 = isrow ? cc : rr;
    float* wdA = &wxs[wv][a0 * SAs + b0 * 8];
    float* wdB = &wxs[wv][(a0 + 8) * SAs + b0 * 8];
    ((float4*)wdA)[0] = float4{aA[0], aA[1], aA[2], aA[3]};
    ((float4*)wdA)[1] = float4{aA[4], aA[5], aA[6], aA[7]};
    ((float4*)wdB)[0] = float4{aB[0], aB[1], aB[2], aB[3]};
    ((float4*)wdB)[1] = float4{aB[4], aB[5], aB[6], aB[7]};
  }
  __builtin_amdgcn_wave_barrier();

  // ---- packed recurrence: seq = rr, hid = cc; v2 = (tile0, tile1) ----
  const int seq = rr, hid = cc;
  v2f u1b[8];
#pragma unroll
  for (int i = 0; i < 8; ++i) u1b[i] = bc(U1[i * 8 + hid]);
  const float bg1v = bg1[hid], bu1v = bu1[hid];
  const float zg1 = frcp(1.f + __expf(-zeta1[0]));
  const float ng1 = frcp(1.f + __expf(-nu1[0]));
  const v2f bgB = bc(bg1v);
  const v2f KB = bc(__expf(2.f * (bg1v - bu1v)));
  const v2f nzgB = bc(-zg1);
  const v2f AB = bc(zg1 + ng1);

  v2f* hq = &hp[wv][0];
  v2f h; h.x = 0.f; h.y = 0.f;
  {  // t = 0
    v2f pre;
    pre.x = wxs[wv][seq * SAs + hid];
    pre.y = wxs[wv][(seq + 8) * SAs + hid];
    h = gate2(pre, h, bgB, KB, nzgB, AB, true);
    hq[seq * SH + hid] = h;
  }
  __builtin_amdgcn_wave_barrier();
#pragma unroll
  for (int t = 1; t < 8; ++t) {
    v2f q = hq[seq * SH + 0] * u1b[0];
#pragma unroll
    for (int i = 1; i < 8; ++i) q = vfma2(hq[seq * SH + i], u1b[i], q);
    v2f pre;
    pre.x = wxs[wv][seq * SAs + t * 8 + hid];
    pre.y = wxs[wv][(seq + 8) * SAs + t * 8 + hid];
    pre = pre + q;
    h = gate2(pre, h, bgB, KB, nzgB, AB, false);
    hq[seq * SH + hid] = h;
    __builtin_amdgcn_wave_barrier();
  }

  // out: [b][t27][y-or-x][hid]; tile0 at k*16+seq, tile1 +8 (= +64 floats)
  const size_t obase = (((size_t)(b * 27 + t27) * 112) + k * 16 + seq) * 8 + hid;
  float* dst = isrow ? hrowg : hcolg;
  dst[obase] = h.x;
  dst[obase + 64] = h.y;
}

// ---------------- Kernel B: level-2, 2 patches (packed) per wave ----------------
__global__ __launch_bounds__(256) void l2_kernel(
    const float* __restrict__ hrowg, const float* __restrict__ hcolg,
    const float* __restrict__ W2, const float* __restrict__ U2,
    const float* __restrict__ bg2, const float* __restrict__ bu2,
    const float* __restrict__ zeta2, const float* __restrict__ nu2,
    float* __restrict__ out) {
  constexpr int GST = 18;  // h2 branch stride (v2 units)
  __shared__ v2f hbI[PPB][128];            // [src2][t8][i8] patch-pair packed
  __shared__ v2f h2I[PPB][3 * GST + 16];

  const int tid = threadIdx.x, wv = tid >> 6, lane = tid & 63;
  const int w = blockIdx.x * PPB + wv;
  const int n0 = 2 * w, n1 = n0 + 1;

  // ---- stage both patches' hrow/hcol blocks, interleaved (p0,p1) ----
  {
    const int p = lane >> 5, half = (lane >> 4) & 1, idx = lane & 15;
    const int pn = p ? n1 : n0;
    const int pw = pn % 27;
    const int qq = pn / 27;
    const int ph = qq % 27, bb = qq / 27;
    const float* src = half ? &hcolg[(((size_t)(bb * 27 + ph)) * 112 + pw * 4) * 8]
                            : &hrowg[(((size_t)(bb * 27 + pw)) * 112 + ph * 4) * 8];
    float4 val = ((const float4*)src)[idx];
    float* base = (float*)&hbI[wv][half * 64 + idx * 4];
    base[0 + p] = val.x;
    base[2 + p] = val.y;
    base[4 + p] = val.z;
    base[6 + p] = val.w;
  }
  __builtin_amdgcn_wave_barrier();

  const int g = lane >> 4, j = lane & 15;
  v2f w2b[8], u2b[16];
#pragma unroll
  for (int d = 0; d < 8; ++d) w2b[d] = bc(W2[d * 16 + j]);
#pragma unroll
  for (int i = 0; i < 16; ++i) u2b[i] = bc(U2[i * 16 + j]);
  const float bg2v = bg2[j], bu2v = bu2[j];
  const float zg2 = frcp(1.f + __expf(-zeta2[0]));
  const float ng2 = frcp(1.f + __expf(-nu2[0]));
  const v2f bgB = bc(bg2v);
  const v2f KB = bc(__expf(2.f * (bg2v - bu2v)));
  const v2f nzgB = bc(-zg2);
  const v2f AB = bc(zg2 + ng2);

  const v2f* hsrc = &hbI[wv][(g >> 1) * 64];
  v2f* h2q = &h2I[wv][g * GST];

  v2f h2; h2.x = 0.f; h2.y = 0.f;
  {  // t = 0
    const int tt = (g & 1) ? 7 : 0;
    v2f p = hsrc[tt * 8 + 0] * w2b[0];
#pragma unroll
    for (int d = 1; d < 8; ++d) p = vfma2(hsrc[tt * 8 + d], w2b[d], p);
    h2 = gate2(p, h2, bgB, KB, nzgB, AB, true);
    h2q[j] = h2;
  }
  __builtin_amdgcn_wave_barrier();
#pragma unroll
  for (int t = 1; t < 8; ++t) {
    const int tt = (g & 1) ? (7 - t) : t;
    v2f p = hsrc[tt * 8 + 0] * w2b[0];
#pragma unroll
    for (int d = 1; d < 8; ++d) p = vfma2(hsrc[tt * 8 + d], w2b[d], p);
    v2f q = h2q[0] * u2b[0];
#pragma unroll
    for (int i = 1; i < 16; ++i) q = vfma2(h2q[i], u2b[i], q);
    v2f pre = p + q;
    h2 = gate2(pre, h2, bgB, KB, nzgB, AB, false);
    if (t < 7) {
      h2q[j] = h2;
      __builtin_amdgcn_wave_barrier();
    }
  }

  out[(size_t)n0 * 64 + lane] = h2.x;
  out[(size_t)n1 * 64 + lane] = h2.y;
}

extern "C" void kernel_launch(void* const* d_in, const int* in_sizes, int n_in,
                              void* d_out, int out_size, void* d_ws, size_t ws_size,
                              hipStream_t stream) {
  const float* inp   = (const float*)d_in[0];
  const float* W1    = (const float*)d_in[1];
  const float* U1    = (const float*)d_in[2];
  const float* bg1   = (const float*)d_in[3];
  const float* bu1   = (const float*)d_in[4];
  const float* zeta1 = (const float*)d_in[5];
  const float* nu1   = (const float*)d_in[6];
  const float* W2    = (const float*)d_in[7];
  const float* U2    = (const float*)d_in[8];
  const float* bg2   = (const float*)d_in[9];
  const float* bu2   = (const float*)d_in[10];
  const float* zeta2 = (const float*)d_in[11];
  const float* nu2   = (const float*)d_in[12];
  float* out = (float*)d_out;

  const size_t HSZ = (size_t)32 * 27 * 112 * 8;  // floats per h buffer
  float* hrowg = (float*)d_ws;
  float* hcolg = hrowg + HSZ;

  // Kernel A: 12096 pair-waves (6048 row + 6048 col), 4/block
  l1_kernel<<<dim3(3024), dim3(256), 0, stream>>>(
      inp, W1, U1, bg1, bu1, zeta1, nu1, hrowg, hcolg);
  // Kernel B: 11664 patch-pair waves, 4/block
  l2_kernel<<<dim3(2916), dim3(256), 0, stream>>>(
      hrowg, hcolg, W2, U2, bg2, bu2, zeta2, nu2, out);
}

// Round 6
// 37.364 us; speedup vs baseline: 2.1273x; 1.0078x over previous
//
#include <hip/hip_runtime.h>

#define PPB 4  // waves per 256-thread block

typedef float v2f __attribute__((ext_vector_type(2)));

__device__ __forceinline__ float frcp(float x) { return __builtin_amdgcn_rcpf(x); }

__device__ __forceinline__ v2f vfma2(v2f a, v2f b, v2f c) {
#if __has_builtin(__builtin_amdgcn_pk_fma_f32)
  return __builtin_amdgcn_pk_fma_f32(a, b, c);
#elif __has_builtin(__builtin_elementwise_fma)
  return __builtin_elementwise_fma(a, b, c);
#else
  v2f d; d.x = fmaf(a.x, b.x, c.x); d.y = fmaf(a.y, b.y, c.y); return d;
#endif
}
__device__ __forceinline__ v2f vmul2(v2f a, v2f b) {
#if __has_builtin(__builtin_amdgcn_pk_mul_f32)
  return __builtin_amdgcn_pk_mul_f32(a, b);
#else
  return a * b;
#endif
}
__device__ __forceinline__ v2f vadd2(v2f a, v2f b) {
#if __has_builtin(__builtin_amdgcn_pk_add_f32)
  return __builtin_amdgcn_pk_add_f32(a, b);
#else
  return a + b;
#endif
}
__device__ __forceinline__ v2f bc(float x) { v2f p; p.x = x; p.y = x; return p; }

// packed FastGRNN gate update (2 independent recurrences per lane)
__device__ __forceinline__ v2f gate2(v2f pre, v2f h, v2f bgB, v2f KB, v2f nzgB,
                                     v2f AB, bool first) {
  v2f a = vadd2(pre, bgB);
  v2f s; s.x = __expf(-a.x); s.y = __expf(-a.y);
  v2f one = bc(1.f);
  v2f zd = vadd2(s, one);
  v2f z; z.x = frcp(zd.x); z.y = frcp(zd.y);
  v2f u = vmul2(vmul2(s, s), KB);
  v2f cd = vadd2(u, one);
  v2f cr; cr.x = frcp(cd.x); cr.y = frcp(cd.y);
  v2f cc = vfma2(cr, bc(2.f), bc(-1.f));
  v2f m = vfma2(z, nzgB, AB);
  v2f mc = vmul2(m, cc);
  return first ? mc : vfma2(z, h, mc);
}

// ---------------- Kernel A: dedup'd level-1, 2 tiles (packed) per wave ----------------
__global__ __launch_bounds__(256) void l1_kernel(
    const float* __restrict__ inp, const float* __restrict__ W1,
    const float* __restrict__ U1, const float* __restrict__ bg1,
    const float* __restrict__ bu1, const float* __restrict__ zeta1,
    const float* __restrict__ nu1, float* __restrict__ hrowg,
    float* __restrict__ hcolg) {
  constexpr int NP = 6048;   // 32 * 7 * 27 pair-waves per mode
  constexpr int SAs = 68;    // wx scalar a-row stride (floats)
  constexpr int SH = 18;     // hp seq stride (v2 units)

  __shared__ float w1s[128];
  __shared__ float wxs[PPB][16 * SAs];
  __shared__ v2f hp[PPB][7 * SH + 8];

  const int tid = threadIdx.x, wv = tid >> 6, lane = tid & 63;
  const int widx = blockIdx.x * PPB + wv;

  if (tid < 32) ((float4*)w1s)[tid] = ((const float4*)W1)[tid];
  __syncthreads();

  const bool isrow = widx < NP;
  const int v = isrow ? widx : widx - NP;
  const int b = v / 189;        // 7*27
  const int rem = v % 189;
  const int k = rem / 27;       // tile-pair index (0..6)
  const int t27 = rem % 27;     // window index

  const int rr = lane >> 3, cc = lane & 7;
  // pixel A (tile0) and B (tile1)
  const int ay = isrow ? (k * 16 + rr) : (t27 * 4 + rr);
  const int ax = isrow ? (t27 * 4 + cc) : (k * 16 + cc);
  const int by = isrow ? (ay + 8) : ay;
  const int bx = isrow ? ax : (ax + 8);

  // ---- wx for both pixels (v2f across j-pairs, weights shared) ----
  {
    const float* pA = inp + ((size_t)(b * 112 + ay) * 112 + ax) * 16;
    const float* pB = inp + ((size_t)(b * 112 + by) * 112 + bx) * 16;
    float4 A0 = ((const float4*)pA)[0], A1 = ((const float4*)pA)[1],
           A2 = ((const float4*)pA)[2], A3 = ((const float4*)pA)[3];
    float4 B0 = ((const float4*)pB)[0], B1 = ((const float4*)pB)[1],
           B2 = ((const float4*)pB)[2], B3 = ((const float4*)pB)[3];
    float xA[16] = {A0.x, A0.y, A0.z, A0.w, A1.x, A1.y, A1.z, A1.w,
                    A2.x, A2.y, A2.z, A2.w, A3.x, A3.y, A3.z, A3.w};
    float xB[16] = {B0.x, B0.y, B0.z, B0.w, B1.x, B1.y, B1.z, B1.w,
                    B2.x, B2.y, B2.z, B2.w, B3.x, B3.y, B3.z, B3.w};
    v2f aA0 = bc(0.f), aA1 = bc(0.f), aA2 = bc(0.f), aA3 = bc(0.f);
    v2f aB0 = bc(0.f), aB1 = bc(0.f), aB2 = bc(0.f), aB3 = bc(0.f);
#pragma unroll
    for (int ci = 0; ci < 16; ++ci) {
      const v2f* wr = (const v2f*)&w1s[ci * 8];
      v2f w0 = wr[0], w1 = wr[1], w2 = wr[2], w3 = wr[3];
      v2f xa = bc(xA[ci]), xb = bc(xB[ci]);
      aA0 = vfma2(xa, w0, aA0); aA1 = vfma2(xa, w1, aA1);
      aA2 = vfma2(xa, w2, aA2); aA3 = vfma2(xa, w3, aA3);
      aB0 = vfma2(xb, w0, aB0); aB1 = vfma2(xb, w1, aB1);
      aB2 = vfma2(xb, w2, aB2); aB3 = vfma2(xb, w3, aB3);
    }
    // store: row-mode (a,b) = (rr,cc); col-mode (a,b) = (cc,rr); tile1 at a+8
    const int a0 = isrow ? rr : cc;
    const int b0 = isrow ? cc : rr;
    float* wdA = &wxs[wv][a0 * SAs + b0 * 8];
    float* wdB = &wxs[wv][(a0 + 8) * SAs + b0 * 8];
    ((float4*)wdA)[0] = float4{aA0.x, aA0.y, aA1.x, aA1.y};
    ((float4*)wdA)[1] = float4{aA2.x, aA2.y, aA3.x, aA3.y};
    ((float4*)wdB)[0] = float4{aB0.x, aB0.y, aB1.x, aB1.y};
    ((float4*)wdB)[1] = float4{aB2.x, aB2.y, aB3.x, aB3.y};
  }
  __builtin_amdgcn_wave_barrier();

  // ---- packed recurrence: seq = rr, hid = cc; v2 = (tile0, tile1) ----
  const int seq = rr, hid = cc;
  v2f u1b[8];
#pragma unroll
  for (int i = 0; i < 8; ++i) u1b[i] = bc(U1[i * 8 + hid]);
  const float bg1v = bg1[hid], bu1v = bu1[hid];
  const float zg1 = frcp(1.f + __expf(-zeta1[0]));
  const float ng1 = frcp(1.f + __expf(-nu1[0]));
  const v2f bgB = bc(bg1v);
  const v2f KB = bc(__expf(2.f * (bg1v - bu1v)));
  const v2f nzgB = bc(-zg1);
  const v2f AB = bc(zg1 + ng1);

  v2f* hq = &hp[wv][0];
  v2f h = bc(0.f);
  {  // t = 0
    v2f pre;
    pre.x = wxs[wv][seq * SAs + hid];
    pre.y = wxs[wv][(seq + 8) * SAs + hid];
    h = gate2(pre, h, bgB, KB, nzgB, AB, true);
    hq[seq * SH + hid] = h;
  }
  __builtin_amdgcn_wave_barrier();
#pragma unroll
  for (int t = 1; t < 8; ++t) {
    const float4* hr4 = (const float4*)&hq[seq * SH];
    float4 f0 = hr4[0], f1 = hr4[1], f2 = hr4[2], f3 = hr4[3];
    v2f q = vmul2(v2f{f0.x, f0.y}, u1b[0]);
    q = vfma2(v2f{f0.z, f0.w}, u1b[1], q);
    q = vfma2(v2f{f1.x, f1.y}, u1b[2], q);
    q = vfma2(v2f{f1.z, f1.w}, u1b[3], q);
    q = vfma2(v2f{f2.x, f2.y}, u1b[4], q);
    q = vfma2(v2f{f2.z, f2.w}, u1b[5], q);
    q = vfma2(v2f{f3.x, f3.y}, u1b[6], q);
    q = vfma2(v2f{f3.z, f3.w}, u1b[7], q);
    v2f pre;
    pre.x = wxs[wv][seq * SAs + t * 8 + hid];
    pre.y = wxs[wv][(seq + 8) * SAs + t * 8 + hid];
    pre = vadd2(pre, q);
    h = gate2(pre, h, bgB, KB, nzgB, AB, false);
    hq[seq * SH + hid] = h;
    __builtin_amdgcn_wave_barrier();
  }

  // out: [b][t27][y-or-x][hid]; tile0 at k*16+seq, tile1 +8 (= +64 floats)
  const size_t obase = (((size_t)(b * 27 + t27) * 112) + k * 16 + seq) * 8 + hid;
  float* dst = isrow ? hrowg : hcolg;
  dst[obase] = h.x;
  dst[obase + 64] = h.y;
}

// ---------------- Kernel B: level-2, 2 patches (packed) per wave ----------------
__global__ __launch_bounds__(256) void l2_kernel(
    const float* __restrict__ hrowg, const float* __restrict__ hcolg,
    const float* __restrict__ W2, const float* __restrict__ U2,
    const float* __restrict__ bg2, const float* __restrict__ bu2,
    const float* __restrict__ zeta2, const float* __restrict__ nu2,
    float* __restrict__ out) {
  constexpr int GST = 18;  // h2 branch stride (v2 units)
  constexpr int WHT = 18;  // wh row stride (v2 units): [src][t][j16 + pad2]
  __shared__ v2f hbI[PPB][128];            // [src2][t8][d8] patch-pair packed
  __shared__ v2f whb[PPB][2 * 8 * WHT];    // precomputed W2.h
  __shared__ v2f h2I[PPB][3 * GST + 16];

  const int tid = threadIdx.x, wv = tid >> 6, lane = tid & 63;
  const int w = blockIdx.x * PPB + wv;
  const int n0 = 2 * w, n1 = n0 + 1;

  // ---- stage both patches' hrow/hcol blocks, interleaved (p0,p1) ----
  {
    const int p = lane >> 5, half = (lane >> 4) & 1, idx = lane & 15;
    const int pn = p ? n1 : n0;
    const int pw = pn % 27;
    const int qq = pn / 27;
    const int ph = qq % 27, bb = qq / 27;
    const float* src = half ? &hcolg[(((size_t)(bb * 27 + ph)) * 112 + pw * 4) * 8]
                            : &hrowg[(((size_t)(bb * 27 + pw)) * 112 + ph * 4) * 8];
    float4 val = ((const float4*)src)[idx];
    float* base = (float*)&hbI[wv][half * 64 + idx * 4];
    base[0 + p] = val.x;
    base[2 + p] = val.y;
    base[4 + p] = val.z;
    base[6 + p] = val.w;
  }
  __builtin_amdgcn_wave_barrier();

  const int g = lane >> 4, j = lane & 15;
  v2f w2b[8], u2b[16];
#pragma unroll
  for (int d = 0; d < 8; ++d) w2b[d] = bc(W2[d * 16 + j]);
#pragma unroll
  for (int i = 0; i < 16; ++i) u2b[i] = bc(U2[i * 16 + j]);
  const float bg2v = bg2[j], bu2v = bu2[j];
  const float zg2 = frcp(1.f + __expf(-zeta2[0]));
  const float ng2 = frcp(1.f + __expf(-nu2[0]));
  const v2f bgB = bc(bg2v);
  const v2f KB = bc(__expf(2.f * (bg2v - bu2v)));
  const v2f nzgB = bc(-zg2);
  const v2f AB = bc(zg2 + ng2);

  const int src = g >> 1;

  // ---- precompute wh[src][t][j] = sum_d h[src][t][d] * W2[d][j] (t-split by g&1) ----
  {
    const v2f* hb = &hbI[wv][src * 64];
    const int t0 = (g & 1) * 4;
#pragma unroll
    for (int i = 0; i < 4; ++i) {
      const int t = t0 + i;
      const v2f* hr = &hb[t * 8];
      v2f p = vmul2(hr[0], w2b[0]);
#pragma unroll
      for (int d = 1; d < 8; ++d) p = vfma2(hr[d], w2b[d], p);
      whb[wv][(src * 8 + t) * WHT + j] = p;
    }
  }
  __builtin_amdgcn_wave_barrier();

  const v2f* whsrc = &whb[wv][src * 8 * WHT];
  v2f* h2q = &h2I[wv][g * GST];

  v2f h2 = bc(0.f);
  {  // t = 0
    const int tt = (g & 1) ? 7 : 0;
    v2f p = whsrc[tt * WHT + j];
    h2 = gate2(p, h2, bgB, KB, nzgB, AB, true);
    h2q[j] = h2;
  }
  __builtin_amdgcn_wave_barrier();
#pragma unroll
  for (int t = 1; t < 8; ++t) {
    const int tt = (g & 1) ? (7 - t) : t;
    v2f p = whsrc[tt * WHT + j];
    const float4* q4 = (const float4*)h2q;
    float4 v0 = q4[0], v1 = q4[1], v2_ = q4[2], v3 = q4[3];
    float4 v4 = q4[4], v5 = q4[5], v6 = q4[6], v7 = q4[7];
    v2f q = vmul2(v2f{v0.x, v0.y}, u2b[0]);
    q = vfma2(v2f{v0.z, v0.w}, u2b[1], q);
    q = vfma2(v2f{v1.x, v1.y}, u2b[2], q);
    q = vfma2(v2f{v1.z, v1.w}, u2b[3], q);
    q = vfma2(v2f{v2_.x, v2_.y}, u2b[4], q);
    q = vfma2(v2f{v2_.z, v2_.w}, u2b[5], q);
    q = vfma2(v2f{v3.x, v3.y}, u2b[6], q);
    q = vfma2(v2f{v3.z, v3.w}, u2b[7], q);
    q = vfma2(v2f{v4.x, v4.y}, u2b[8], q);
    q = vfma2(v2f{v4.z, v4.w}, u2b[9], q);
    q = vfma2(v2f{v5.x, v5.y}, u2b[10], q);
    q = vfma2(v2f{v5.z, v5.w}, u2b[11], q);
    q = vfma2(v2f{v6.x, v6.y}, u2b[12], q);
    q = vfma2(v2f{v6.z, v6.w}, u2b[13], q);
    q = vfma2(v2f{v7.x, v7.y}, u2b[14], q);
    q = vfma2(v2f{v7.z, v7.w}, u2b[15], q);
    v2f pre = vadd2(p, q);
    h2 = gate2(pre, h2, bgB, KB, nzgB, AB, false);
    if (t < 7) {
      h2q[j] = h2;
      __builtin_amdgcn_wave_barrier();
    }
  }

  out[(size_t)n0 * 64 + lane] = h2.x;
  out[(size_t)n1 * 64 + lane] = h2.y;
}

extern "C" void kernel_launch(void* const* d_in, const int* in_sizes, int n_in,
                              void* d_out, int out_size, void* d_ws, size_t ws_size,
                              hipStream_t stream) {
  const float* inp   = (const float*)d_in[0];
  const float* W1    = (const float*)d_in[1];
  const float* U1    = (const float*)d_in[2];
  const float* bg1   = (const float*)d_in[3];
  const float* bu1   = (const float*)d_in[4];
  const float* zeta1 = (const float*)d_in[5];
  const float* nu1   = (const float*)d_in[6];
  const float* W2    = (const float*)d_in[7];
  const float* U2    = (const float*)d_in[8];
  const float* bg2   = (const float*)d_in[9];
  const float* bu2   = (const float*)d_in[10];
  const float* zeta2 = (const float*)d_in[11];
  const float* nu2   = (const float*)d_in[12];
  float* out = (float*)d_out;

  const size_t HSZ = (size_t)32 * 27 * 112 * 8;  // floats per h buffer
  float* hrowg = (float*)d_ws;
  float* hcolg = hrowg + HSZ;

  // Kernel A: 12096 pair-waves (6048 row + 6048 col), 4/block
  l1_kernel<<<dim3(3024), dim3(256), 0, stream>>>(
      inp, W1, U1, bg1, bu1, zeta1, nu1, hrowg, hcolg);
  // Kernel B: 11664 patch-pair waves, 4/block
  l2_kernel<<<dim3(2916), dim3(256), 0, stream>>>(
      hrowg, hcolg, W2, U2, bg2, bu2, zeta2, nu2, out);
}